// Round 2
// baseline (1191.095 us; speedup 1.0000x reference)
//
#include <hip/hip_runtime.h>
#include <math.h>

typedef _Float16 f16x2 __attribute__((ext_vector_type(2)));
typedef _Float16 f16x4 __attribute__((ext_vector_type(4)));
typedef _Float16 f16x8 __attribute__((ext_vector_type(8)));

__device__ __forceinline__ float fdot2(f16x2 a, f16x2 b, float c) {
#if defined(__has_builtin)
#if __has_builtin(__builtin_amdgcn_fdot2)
  return __builtin_amdgcn_fdot2(a, b, c, false);
#else
  return c + (float)a[0] * (float)b[0] + (float)a[1] * (float)b[1];
#endif
#else
  return c + (float)a[0] * (float)b[0] + (float)a[1] * (float)b[1];
#endif
}

__device__ __forceinline__ float sigmoidf_(float v) {
  return 1.0f / (1.0f + __expf(-v));
}
__device__ __forceinline__ float tanhf_(float v) {
  v = fminf(fmaxf(v, -15.f), 15.f);
  float e = __expf(2.f * v);
  return (e - 1.f) / (e + 1.f);
}

#define WSTR 196  // weight LDS row stride in f16x2 units
#define XSTR 65   // data LDS row stride

// ---------------- fuse conv into GRU input weights: Wc[j][c] = sum_k W[c][k] * w_ih[j][k] ----------------
// grid = 5 layers * 4 j-quarters; block 256
__global__ __launch_bounds__(256) void fuse_w_kernel(const float* __restrict__ conv_w,
                                                     const float* __restrict__ w_ih,
                                                     float* __restrict__ wc) {
  const int l = blockIdx.x >> 2;
  const int j0 = (blockIdx.x & 3) * 48;
  const float* W = conv_w + (size_t)l * 4096;       // [c][k]
  const float* wi = w_ih + (size_t)l * 12288;       // [j][k]
  float* out = wc + (size_t)l * 12288;              // [j][c]
  __shared__ float sWt[64 * 68];  // transposed: sWt[k*68+c] = W[c][k]
  __shared__ float sI[48 * 64];
  const int t = threadIdx.x;
  for (int i = t; i < 4096; i += 256) sWt[(i & 63) * 68 + (i >> 6)] = W[i];
  for (int i = t; i < 3072; i += 256) sI[i] = wi[j0 * 64 + i];
  __syncthreads();
#pragma unroll
  for (int r = 0; r < 3; ++r) {
    int u = t + 256 * r;       // 768 units = 48 j * 16 c-groups
    int j = u >> 4, cg = (u & 15) * 4;
    float4 a = {0.f, 0.f, 0.f, 0.f};
    for (int k = 0; k < 64; ++k) {
      float4 w = *(const float4*)(sWt + k * 68 + cg);
      float s = sI[j * 64 + k];
      a.x += w.x * s; a.y += w.y * s; a.z += w.z * s; a.w += w.w * s;
    }
    *(float4*)(out + (size_t)(j0 + j) * 64 + cg) = a;
  }
}

// ---------------- bucketed CSR build (buckets of 128 nodes by dst) ----------------
__global__ __launch_bounds__(256) void bucket_hist_kernel(const int* __restrict__ dst,
                                                          int* __restrict__ bh, int E, int nb) {
  __shared__ int h[1024];
  const int t = threadIdx.x;
  for (int i = t; i < nb; i += 256) h[i] = 0;
  __syncthreads();
  for (int e = blockIdx.x * 256 + t; e < E; e += gridDim.x * 256)
    atomicAdd(&h[dst[e] >> 7], 1);
  __syncthreads();
  for (int i = t; i < nb; i += 256) {
    int v = h[i];
    if (v) atomicAdd(&bh[i], v);
  }
}

__global__ __launch_bounds__(1024) void bucket_scan_kernel(const int* __restrict__ bh, int nb,
                                                           int* __restrict__ boffs,
                                                           int* __restrict__ bcur, int E) {
  __shared__ int s[1024];
  const int t = threadIdx.x;
  int v = (t < nb) ? bh[t] : 0;
  s[t] = v;
  __syncthreads();
  for (int o = 1; o < 1024; o <<= 1) {
    int a = (t >= o) ? s[t - o] : 0;
    __syncthreads();
    s[t] += a;
    __syncthreads();
  }
  if (t < nb) {
    int ex = s[t] - v;
    boffs[t] = ex;
    bcur[t] = ex;
  }
  if (t == 0) boffs[nb] = E;
}

__global__ __launch_bounds__(256) void bucket_fill_kernel(const int* __restrict__ src,
                                                          const int* __restrict__ dst,
                                                          int* __restrict__ bcur,
                                                          uint2* __restrict__ pairs, int E) {
  int e = blockIdx.x * 256 + threadIdx.x;
  if (e < E) {
    int d = dst[e];
    int pos = atomicAdd(&bcur[d >> 7], 1);
    pairs[pos] = make_uint2((unsigned)src[e], (unsigned)d);
  }
}

// one block per bucket: counting-sort within bucket; contiguous offs/srcs writes
__global__ __launch_bounds__(256) void csr_build_kernel(const uint2* __restrict__ pairs,
                                                        const int* __restrict__ boffs,
                                                        int* __restrict__ offs,
                                                        int* __restrict__ srcs, int N, int E) {
  const int b = blockIdx.x;
  const int nbase = b << 7;
  __shared__ int deg[128], cur[128], sc[128];
  const int t = threadIdx.x;
  if (t < 128) deg[t] = 0;
  __syncthreads();
  const int beg = boffs[b], end = boffs[b + 1];
  for (int e = beg + t; e < end; e += 256) atomicAdd(&deg[pairs[e].y & 127], 1);
  __syncthreads();
  if (t < 128) sc[t] = deg[t];
  __syncthreads();
  for (int o = 1; o < 128; o <<= 1) {
    int a = 0;
    if (t < 128 && t >= o) a = sc[t - o];
    __syncthreads();
    if (t < 128) sc[t] += a;
    __syncthreads();
  }
  if (t < 128) {
    int node = nbase + t;
    if (node < N) {
      int ex = beg + sc[t] - deg[t];
      offs[node] = ex;
      cur[t] = ex;
    }
  }
  if (b == 0 && t == 0) offs[N] = E;
  __syncthreads();
  for (int e = beg + t; e < end; e += 256) {
    uint2 p = pairs[e];
    int pos = atomicAdd(&cur[p.y & 127], 1);
    srcs[pos] = (int)p.x;
  }
}

// ---------------- aggregate raw x (f16): agg[v] = sum_{e in CSR[v]} x[srcs[e]] ----------------
__global__ __launch_bounds__(256) void agg_kernel(const _Float16* __restrict__ xh,
                                                  const int* __restrict__ offs,
                                                  const int* __restrict__ srcs,
                                                  float* __restrict__ agg, int N) {
  int wave = threadIdx.x >> 6, lane = threadIdx.x & 63;
  int v = blockIdx.x * 4 + wave;
  if (v >= N) return;
  int beg = offs[v], end = offs[v + 1];
  float acc = 0.f;
  int e = beg;
  for (; e + 4 <= end; e += 4) {
    int s0 = srcs[e], s1 = srcs[e + 1], s2 = srcs[e + 2], s3 = srcs[e + 3];
    float a0 = (float)xh[(size_t)s0 * 64 + lane];
    float a1 = (float)xh[(size_t)s1 * 64 + lane];
    float a2 = (float)xh[(size_t)s2 * 64 + lane];
    float a3 = (float)xh[(size_t)s3 * 64 + lane];
    acc += a0 + a1 + a2 + a3;
  }
  for (; e < end; ++e) acc += (float)xh[(size_t)srcs[e] * 64 + lane];
  agg[(size_t)v * 64 + lane] = acc;
}

// ---------------- fused GRU: x = GRUCell(agg @ (implicit Wc), x); also writes f16 copy ----------------
__global__ __launch_bounds__(256) void gru_kernel(const float* __restrict__ agg,
                                                  float* __restrict__ x,
                                                  _Float16* __restrict__ xh,
                                                  const float* __restrict__ w_ih,
                                                  const float* __restrict__ w_hh,
                                                  const float* __restrict__ b_ih,
                                                  const float* __restrict__ b_hh,
                                                  int N, int numTiles) {
  __shared__ f16x2 sWih[32 * WSTR];
  __shared__ f16x2 sWhh[32 * WSTR];
  __shared__ f16x2 sA[16 * XSTR];
  __shared__ f16x2 sH[16 * XSTR];
  const int t = threadIdx.x;
  {
    const int k2 = t & 31, jb = t >> 5;
    for (int j = jb; j < 192; j += 8) {
      float2 wi = *(const float2*)(w_ih + j * 64 + 2 * k2);
      float2 wh = *(const float2*)(w_hh + j * 64 + 2 * k2);
      f16x2 a, b;
      a[0] = (_Float16)wi.x;
      a[1] = (_Float16)wi.y;
      b[0] = (_Float16)wh.x;
      b[1] = (_Float16)wh.y;
      sWih[k2 * WSTR + j] = a;
      sWhh[k2 * WSTR + j] = b;
    }
  }
  const int dq = t & 15, nq = t >> 4;
  const int d0 = dq * 4;
  for (int tile = blockIdx.x; tile < numTiles; tile += gridDim.x) {
    const int nbase = tile * 64;
    float acc[6][4][4];
#pragma unroll
    for (int gg = 0; gg < 6; ++gg)
#pragma unroll
      for (int ni = 0; ni < 4; ++ni)
#pragma unroll
        for (int di = 0; di < 4; ++di) acc[gg][ni][di] = 0.f;
#pragma unroll
    for (int half = 0; half < 2; ++half) {
      __syncthreads();
      {
        const int k2s = t & 15, ns = t >> 4;
        for (int nn = ns; nn < 64; nn += 16) {
          const int node = nbase + nn;
          float2 av = {0.f, 0.f}, hv = {0.f, 0.f};
          if (node < N) {
            av = *(const float2*)(agg + (size_t)node * 64 + half * 32 + 2 * k2s);
            hv = *(const float2*)(x + (size_t)node * 64 + half * 32 + 2 * k2s);
          }
          f16x2 a, h;
          a[0] = (_Float16)av.x;
          a[1] = (_Float16)av.y;
          h[0] = (_Float16)hv.x;
          h[1] = (_Float16)hv.y;
          sA[k2s * XSTR + nn] = a;
          sH[k2s * XSTR + nn] = h;
        }
      }
      __syncthreads();
      for (int k2 = 0; k2 < 16; ++k2) {
        const int kk = half * 16 + k2;
        f16x8 wir = *(const f16x8*)(sWih + kk * WSTR + 0 + d0);
        f16x8 wiz = *(const f16x8*)(sWih + kk * WSTR + 64 + d0);
        f16x8 win = *(const f16x8*)(sWih + kk * WSTR + 128 + d0);
        f16x8 whr = *(const f16x8*)(sWhh + kk * WSTR + 0 + d0);
        f16x8 whz = *(const f16x8*)(sWhh + kk * WSTR + 64 + d0);
        f16x8 whn = *(const f16x8*)(sWhh + kk * WSTR + 128 + d0);
#pragma unroll
        for (int ni = 0; ni < 4; ++ni) {
          f16x2 a = sA[k2 * XSTR + nq * 4 + ni];
          f16x2 h = sH[k2 * XSTR + nq * 4 + ni];
#pragma unroll
          for (int di = 0; di < 4; ++di) {
            f16x2 w;
            w[0] = wir[2 * di]; w[1] = wir[2 * di + 1];
            acc[0][ni][di] = fdot2(a, w, acc[0][ni][di]);
            w[0] = wiz[2 * di]; w[1] = wiz[2 * di + 1];
            acc[1][ni][di] = fdot2(a, w, acc[1][ni][di]);
            w[0] = win[2 * di]; w[1] = win[2 * di + 1];
            acc[2][ni][di] = fdot2(a, w, acc[2][ni][di]);
            w[0] = whr[2 * di]; w[1] = whr[2 * di + 1];
            acc[3][ni][di] = fdot2(h, w, acc[3][ni][di]);
            w[0] = whz[2 * di]; w[1] = whz[2 * di + 1];
            acc[4][ni][di] = fdot2(h, w, acc[4][ni][di]);
            w[0] = whn[2 * di]; w[1] = whn[2 * di + 1];
            acc[5][ni][di] = fdot2(h, w, acc[5][ni][di]);
          }
        }
      }
    }
#pragma unroll
    for (int ni = 0; ni < 4; ++ni) {
      int node = nbase + nq * 4 + ni;
      if (node < N) {
        float4 hold = *(const float4*)(x + (size_t)node * 64 + d0);
        float ho[4] = {hold.x, hold.y, hold.z, hold.w};
        float out[4];
#pragma unroll
        for (int di = 0; di < 4; ++di) {
          int d = d0 + di;
          float ir = acc[0][ni][di] + b_ih[d];
          float iz = acc[1][ni][di] + b_ih[64 + d];
          float in_ = acc[2][ni][di] + b_ih[128 + d];
          float hr = acc[3][ni][di] + b_hh[d];
          float hz = acc[4][ni][di] + b_hh[64 + d];
          float hn = acc[5][ni][di] + b_hh[128 + d];
          float r = sigmoidf_(ir + hr);
          float z = sigmoidf_(iz + hz);
          float nn = tanhf_(in_ + r * hn);
          out[di] = (1.f - z) * nn + z * ho[di];
        }
        float4 v;
        v.x = out[0]; v.y = out[1]; v.z = out[2]; v.w = out[3];
        *(float4*)(x + (size_t)node * 64 + d0) = v;
        f16x4 hv;
        hv[0] = (_Float16)out[0]; hv[1] = (_Float16)out[1];
        hv[2] = (_Float16)out[2]; hv[3] = (_Float16)out[3];
        *(f16x4*)(xh + (size_t)node * 64 + d0) = hv;
      }
    }
  }
}

// ---------------- pooling (batch is sorted -> run-length + few atomics) ----------------
__global__ __launch_bounds__(256) void pool_kernel(const float* __restrict__ x,
                                                   const int* __restrict__ batch,
                                                   float* __restrict__ g, int N) {
  int wave = threadIdx.x >> 6, lane = threadIdx.x & 63;
  int n0 = blockIdx.x * 64 + wave * 16;
  if (n0 >= N) return;
  int end = n0 + 16;
  if (end > N) end = N;
  int cur = batch[n0];
  float acc = 0.f;
  for (int n = n0; n < end; ++n) {
    int b = batch[n];
    if (b != cur) {
      atomicAdd(&g[(size_t)cur * 64 + lane], acc);
      acc = 0.f;
      cur = b;
    }
    acc += x[(size_t)n * 64 + lane];
  }
  atomicAdd(&g[(size_t)cur * 64 + lane], acc);
}

// ---------------- final MLP ----------------
__device__ __forceinline__ float eluf_(float v) { return v > 0.f ? v : (__expf(v) - 1.f); }

__global__ __launch_bounds__(256) void mlp_kernel(const float* __restrict__ g,
                                                  const float* __restrict__ w1,
                                                  const float* __restrict__ b1,
                                                  const float* __restrict__ w2,
                                                  const float* __restrict__ b2,
                                                  const float* __restrict__ w3,
                                                  const float* __restrict__ b3,
                                                  float* __restrict__ out, int G) {
  __shared__ float sG[64 * 64];
  __shared__ float sH1[64 * 32];
  __shared__ float sH2[64 * 16];
  int t = threadIdx.x;
  for (int i = t; i < G * 64; i += 256) sG[i] = g[i];
  __syncthreads();
  for (int o = t; o < G * 32; o += 256) {
    int gi = o >> 5, i = o & 31;
    float a = b1[i];
    for (int k = 0; k < 64; ++k) a += sG[gi * 64 + k] * w1[i * 64 + k];
    sH1[gi * 32 + i] = eluf_(a);
  }
  __syncthreads();
  for (int o = t; o < G * 16; o += 256) {
    int gi = o >> 4, i = o & 15;
    float a = b2[i];
    for (int k = 0; k < 32; ++k) a += sH1[gi * 32 + k] * w2[i * 32 + k];
    sH2[gi * 16 + i] = eluf_(a);
  }
  __syncthreads();
  for (int o = t; o < G; o += 256) {
    float a = b3[0];
    for (int k = 0; k < 16; ++k) a += sH2[o * 16 + k] * w3[k];
    out[o] = a;
  }
}

extern "C" void kernel_launch(void* const* d_in, const int* in_sizes, int n_in,
                              void* d_out, int out_size, void* d_ws, size_t ws_size,
                              hipStream_t stream) {
  const float* conv_w = (const float*)d_in[0];
  const float* w_ih = (const float*)d_in[1];
  const float* w_hh = (const float*)d_in[2];
  const float* b_ih = (const float*)d_in[3];
  const float* b_hh = (const float*)d_in[4];
  const float* fc1_w = (const float*)d_in[5];
  const float* fc1_b = (const float*)d_in[6];
  const float* fc2_w = (const float*)d_in[7];
  const float* fc2_b = (const float*)d_in[8];
  const float* fc3_w = (const float*)d_in[9];
  const float* fc3_b = (const float*)d_in[10];
  const int* ei = (const int*)d_in[11];
  const int* batch = (const int*)d_in[12];
  const int N = in_sizes[12];
  const int E = in_sizes[11] / 2;
  const int G = out_size;
  const int* src = ei;
  const int* dst = ei + E;
  const int nbk = (N + 127) >> 7;  // buckets of 128 nodes (must be <= 1024)

  char* ws = (char*)d_ws;
  size_t off = 0;
  auto alloc = [&](size_t bytes) -> void* {
    void* p = ws + off;
    off += (bytes + 255) & ~(size_t)255;
    return p;
  };
  float* x = (float*)alloc((size_t)N * 64 * 4);
  _Float16* xh = (_Float16*)alloc((size_t)N * 64 * 2);
  float* agg = (float*)alloc((size_t)N * 64 * 4);
  float* wc = (float*)alloc((size_t)5 * 192 * 64 * 4);
  float* gbuf = (float*)alloc((size_t)G * 64 * 4);
  int* offs = (int*)alloc((size_t)(N + 1) * 4);
  int* srcs = (int*)alloc((size_t)E * 4);
  uint2* pairs = (uint2*)alloc((size_t)E * 8);
  int* bh = (int*)alloc(1025 * 4);
  int* boffs = (int*)alloc(1025 * 4);
  int* bcur = (int*)alloc(1025 * 4);

  const int EB = (E + 255) / 256;
  const int tiles = (N + 63) / 64;

  // CSR build (bucketed counting sort by dst)
  hipMemsetAsync(bh, 0, (size_t)nbk * 4, stream);
  bucket_hist_kernel<<<256, 256, 0, stream>>>(dst, bh, E, nbk);
  bucket_scan_kernel<<<1, 1024, 0, stream>>>(bh, nbk, boffs, bcur, E);
  bucket_fill_kernel<<<EB, 256, 0, stream>>>(src, dst, bcur, pairs, E);
  csr_build_kernel<<<nbk, 256, 0, stream>>>(pairs, boffs, offs, srcs, N, E);

  // fold conv weights into GRU input weights: wc[l] = conv_w[l] @ w_ih[l]^T
  fuse_w_kernel<<<20, 256, 0, stream>>>(conv_w, w_ih, wc);

  // layer 0: x=0 -> agg=0; just GRU on zeros
  hipMemsetAsync(x, 0, (size_t)N * 64 * 4, stream);
  hipMemsetAsync(agg, 0, (size_t)N * 64 * 4, stream);
  gru_kernel<<<1024, 256, 0, stream>>>(agg, x, xh, wc, w_hh, b_ih, b_hh, N, tiles);

  for (int l = 1; l < 5; ++l) {
    agg_kernel<<<(N + 3) / 4, 256, 0, stream>>>(xh, offs, srcs, agg, N);
    gru_kernel<<<1024, 256, 0, stream>>>(agg, x, xh, wc + (size_t)l * 12288,
                                         w_hh + (size_t)l * 12288, b_ih + (size_t)l * 192,
                                         b_hh + (size_t)l * 192, N, tiles);
  }

  hipMemsetAsync(gbuf, 0, (size_t)G * 64 * 4, stream);
  pool_kernel<<<(N + 63) / 64, 256, 0, stream>>>(x, batch, gbuf, N);
  mlp_kernel<<<1, 256, 0, stream>>>(gbuf, fc1_w, fc1_b, fc2_w, fc2_b, fc3_w, fc3_b,
                                    (float*)d_out, G);
}

// Round 4
// 607.522 us; speedup vs baseline: 1.9606x; 1.9606x over previous
//
#include <hip/hip_runtime.h>
#include <math.h>

typedef _Float16 f16x2 __attribute__((ext_vector_type(2)));
typedef _Float16 f16x4 __attribute__((ext_vector_type(4)));
typedef _Float16 f16x8 __attribute__((ext_vector_type(8)));
typedef float f32x4 __attribute__((ext_vector_type(4)));

#define CBITS 10      // 1024 nodes per coarse bucket
#define FCHUNK 4096   // edges per fill block (32KB LDS staging)
#define WROW 72       // LDS weight row stride in f16 (64 + 8 pad; 16B aligned, 2-way banks = free)

__device__ __forceinline__ float sigmoidf_(float v) {
  return 1.0f / (1.0f + __expf(-v));
}
__device__ __forceinline__ float tanhf_(float v) {
  v = fminf(fmaxf(v, -15.f), 15.f);
  float e = __expf(2.f * v);
  return (e - 1.f) / (e + 1.f);
}
__device__ __forceinline__ float eluf_(float v) { return v > 0.f ? v : (__expf(v) - 1.f); }

// ---------------- fuse conv into GRU input weights: Wc[j][c] = sum_k W[c][k] * w_ih[j][k] ----------------
__global__ __launch_bounds__(256) void fuse_w_kernel(const float* __restrict__ conv_w,
                                                     const float* __restrict__ w_ih,
                                                     float* __restrict__ wc) {
  const int l = blockIdx.x >> 2;
  const int j0 = (blockIdx.x & 3) * 48;
  const float* W = conv_w + (size_t)l * 4096;   // [c][k]
  const float* wi = w_ih + (size_t)l * 12288;   // [j][k]
  float* out = wc + (size_t)l * 12288;          // [j][c]
  __shared__ float sWt[64 * 68];
  __shared__ float sI[48 * 64];
  const int t = threadIdx.x;
  for (int i = t; i < 4096; i += 256) sWt[(i & 63) * 68 + (i >> 6)] = W[i];
  for (int i = t; i < 3072; i += 256) sI[i] = wi[j0 * 64 + i];
  __syncthreads();
#pragma unroll
  for (int r = 0; r < 3; ++r) {
    int u = t + 256 * r;
    int j = u >> 4, cg = (u & 15) * 4;
    float4 a = {0.f, 0.f, 0.f, 0.f};
    for (int k = 0; k < 64; ++k) {
      float4 w = *(const float4*)(sWt + k * 68 + cg);
      float s = sI[j * 64 + k];
      a.x += w.x * s; a.y += w.y * s; a.z += w.z * s; a.w += w.w * s;
    }
    *(float4*)(out + (size_t)(j0 + j) * 64 + cg) = a;
  }
}

// ---------------- CSR build: coarse-bucket counting sort ----------------
__global__ __launch_bounds__(256) void bucket_hist_kernel(const int* __restrict__ dst,
                                                          int* __restrict__ bh, int E) {
  __shared__ int h[128];
  const int t = threadIdx.x;
  if (t < 128) h[t] = 0;
  __syncthreads();
  for (int e = blockIdx.x * 256 + t; e < E; e += gridDim.x * 256)
    atomicAdd(&h[dst[e] >> CBITS], 1);
  __syncthreads();
  if (t < 128 && h[t]) atomicAdd(&bh[t * 16], h[t]);  // padded counters: 1 line each
}

__global__ __launch_bounds__(128) void bucket_scan_kernel(int* __restrict__ bh, int nbk,
                                                          int* __restrict__ boffs, int E) {
  __shared__ int s[128];
  const int t = threadIdx.x;
  int v = (t < nbk) ? bh[t * 16] : 0;
  s[t] = v;
  __syncthreads();
  for (int o = 1; o < 128; o <<= 1) {
    int a = (t >= o) ? s[t - o] : 0;
    __syncthreads();
    s[t] += a;
    __syncthreads();
  }
  if (t < nbk) {
    int ex = s[t] - v;
    boffs[t] = ex;
    bh[t * 16] = ex;  // becomes the reservation cursor
  }
  if (t == 0) boffs[nbk] = E;
}

__global__ __launch_bounds__(256) void bucket_fill_kernel(const int* __restrict__ src,
                                                          const int* __restrict__ dst,
                                                          int* __restrict__ bcur,
                                                          uint2* __restrict__ pairs, int E) {
  __shared__ uint2 staged[FCHUNK];
  __shared__ int h[128], lbase[128], gbase[128], lcur[128];
  const int t = threadIdx.x;
  const int e0 = blockIdx.x * FCHUNK;
  int cnt = E - e0;
  if (cnt > FCHUNK) cnt = FCHUNK;
  if (t < 128) h[t] = 0;
  __syncthreads();
  for (int i = t; i < cnt; i += 256) atomicAdd(&h[dst[e0 + i] >> CBITS], 1);
  __syncthreads();
  if (t < 128) lcur[t] = h[t];
  __syncthreads();
  for (int o = 1; o < 128; o <<= 1) {
    int a = 0;
    if (t < 128 && t >= o) a = lcur[t - o];
    __syncthreads();
    if (t < 128) lcur[t] += a;
    __syncthreads();
  }
  if (t < 128) {
    int ex = lcur[t] - h[t];
    lbase[t] = ex;
    if (h[t]) gbase[t] = atomicAdd(&bcur[t * 16], h[t]);
    lcur[t] = ex;
  }
  __syncthreads();
  for (int i = t; i < cnt; i += 256) {
    int d = dst[e0 + i];
    int b = d >> CBITS;
    int p = atomicAdd(&lcur[b], 1);
    staged[p] = make_uint2((unsigned)src[e0 + i], (unsigned)d);
  }
  __syncthreads();
  // flush: consecutive i within a bucket -> consecutive global positions (coalesced runs)
  for (int i = t; i < cnt; i += 256) {
    uint2 pr = staged[i];
    int b = (int)(pr.y >> CBITS);
    pairs[gbase[b] + (i - lbase[b])] = pr;
  }
}

__global__ __launch_bounds__(256) void csr_build_kernel(const uint2* __restrict__ pairs,
                                                        const int* __restrict__ boffs,
                                                        int* __restrict__ offs,
                                                        int* __restrict__ srcs, int N, int E) {
  const int b = blockIdx.x, t = threadIdx.x;
  const int nbase = b << CBITS;
  __shared__ int deg[1024];
  __shared__ int ssc[256];
  for (int i = t; i < 1024; i += 256) deg[i] = 0;
  __syncthreads();
  const int beg = boffs[b], end = boffs[b + 1];
  for (int e = beg + t; e < end; e += 256) atomicAdd(&deg[pairs[e].y & 1023], 1);
  __syncthreads();
  int d0 = deg[4 * t], d1 = deg[4 * t + 1], d2 = deg[4 * t + 2], d3 = deg[4 * t + 3];
  int s = d0 + d1 + d2 + d3;
  ssc[t] = s;
  __syncthreads();
  for (int o = 1; o < 256; o <<= 1) {
    int a = (t >= o) ? ssc[t - o] : 0;
    __syncthreads();
    ssc[t] += a;
    __syncthreads();
  }
  int base = beg + ssc[t] - s;
  int c0 = base, c1 = c0 + d0, c2 = c1 + d1, c3 = c2 + d2;
  if (nbase + 4 * t + 0 < N) offs[nbase + 4 * t + 0] = c0;
  if (nbase + 4 * t + 1 < N) offs[nbase + 4 * t + 1] = c1;
  if (nbase + 4 * t + 2 < N) offs[nbase + 4 * t + 2] = c2;
  if (nbase + 4 * t + 3 < N) offs[nbase + 4 * t + 3] = c3;
  deg[4 * t] = c0; deg[4 * t + 1] = c1; deg[4 * t + 2] = c2; deg[4 * t + 3] = c3;
  if (b == 0 && t == 0) offs[N] = E;
  __syncthreads();
  // scatter within this bucket's ~64KB window: absorbed by the local XCD L2
  for (int e = beg + t; e < end; e += 256) {
    uint2 p = pairs[e];
    int pos = atomicAdd(&deg[p.y & 1023], 1);
    srcs[pos] = (int)p.x;
  }
}

// ---------------- layer-0 algebra: h1 = GRU(0, 0) is one 64-vector ----------------
__global__ __launch_bounds__(64) void h1_kernel(const float* __restrict__ b_ih,
                                                const float* __restrict__ b_hh,
                                                float* __restrict__ h1) {
  int d = threadIdx.x;
  float r = sigmoidf_(b_ih[d] + b_hh[d]);
  float z = sigmoidf_(b_ih[64 + d] + b_hh[64 + d]);
  float n = tanhf_(b_ih[128 + d] + r * b_hh[128 + d]);
  h1[d] = (1.f - z) * n;
}

__global__ __launch_bounds__(256) void bcast_kernel(const float* __restrict__ h1,
                                                    float* __restrict__ x,
                                                    _Float16* __restrict__ xh, int units) {
  int idx = blockIdx.x * 256 + threadIdx.x;  // one float4 (4 dims) per thread
  if (idx >= units) return;
  int c4 = idx & 15;
  float4 v = *(const float4*)(h1 + c4 * 4);
  *(float4*)(x + (size_t)idx * 4) = v;
  f16x4 hv;
  hv[0] = (_Float16)v.x; hv[1] = (_Float16)v.y; hv[2] = (_Float16)v.z; hv[3] = (_Float16)v.w;
  *(f16x4*)(xh + (size_t)idx * 4) = hv;
}

// layer-1 aggregate: agg[v] = deg[v] * h1   (all neighbors have identical features)
__global__ __launch_bounds__(256) void aggdeg_kernel(const int* __restrict__ offs,
                                                     const float* __restrict__ h1,
                                                     _Float16* __restrict__ aggh, int N, int Npad) {
  int wave = threadIdx.x >> 6, lane = threadIdx.x & 63;
  int v = blockIdx.x * 4 + wave;
  if (v >= Npad) return;
  float dg = (v < N) ? (float)(offs[v + 1] - offs[v]) : 0.f;
  aggh[(size_t)v * 64 + lane] = (_Float16)(dg * h1[lane]);
}

// ---------------- aggregate raw x (f16 gather): aggh[v] = sum_{e} xh[srcs[e]] ----------------
__global__ __launch_bounds__(256) void agg_kernel(const _Float16* __restrict__ xh,
                                                  const int* __restrict__ offs,
                                                  const int* __restrict__ srcs,
                                                  _Float16* __restrict__ aggh, int N) {
  int wave = threadIdx.x >> 6, lane = threadIdx.x & 63;
  int v = blockIdx.x * 4 + wave;
  if (v >= N) return;
  int beg = offs[v], end = offs[v + 1];
  float acc = 0.f;
  int e = beg;
  for (; e + 4 <= end; e += 4) {
    int s0 = srcs[e], s1 = srcs[e + 1], s2 = srcs[e + 2], s3 = srcs[e + 3];
    float a0 = (float)xh[(size_t)s0 * 64 + lane];
    float a1 = (float)xh[(size_t)s1 * 64 + lane];
    float a2 = (float)xh[(size_t)s2 * 64 + lane];
    float a3 = (float)xh[(size_t)s3 * 64 + lane];
    acc += a0 + a1 + a2 + a3;
  }
  for (; e < end; ++e) acc += (float)xh[(size_t)srcs[e] * 64 + lane];
  aggh[(size_t)v * 64 + lane] = (_Float16)acc;
}

// ---------------- MFMA GRU: x = GRUCell(aggh @ Wc^T, x) ----------------
// Per wave: 16 nodes, all 192 output dims. A-frags from global f16 rows, B-frags from LDS.
__global__ __launch_bounds__(256) void gru_kernel(const _Float16* __restrict__ aggh,
                                                  float* __restrict__ x,
                                                  _Float16* __restrict__ xh,
                                                  const float* __restrict__ wih,
                                                  const float* __restrict__ whh,
                                                  const float* __restrict__ b_ih,
                                                  const float* __restrict__ b_hh,
                                                  int N, int numTiles) {
  __shared__ _Float16 sW[2 * 192 * WROW];  // 54 KB
  const int t = threadIdx.x;
  // stage weights: 2 mats * 192 rows * 16 float4-units = 6144 units (3072 per mat)
  for (int i = t; i < 6144; i += 256) {
    int mat = (i >= 3072) ? 1 : 0;
    int r = (i - mat * 3072) >> 4;
    int c4 = i & 15;
    const float* srcp = (mat ? whh : wih) + r * 64 + c4 * 4;
    float4 v = *(const float4*)srcp;
    f16x4 hv;
    hv[0] = (_Float16)v.x; hv[1] = (_Float16)v.y;
    hv[2] = (_Float16)v.z; hv[3] = (_Float16)v.w;
    *(f16x4*)(sW + mat * 192 * WROW + r * WROW + c4 * 4) = hv;
  }
  __syncthreads();
  const int wave = t >> 6, lane = t & 63;
  const int q = lane >> 4, c = lane & 15;
  float bir[4], biz[4], bin[4], bhr[4], bhz[4], bhn[4];
#pragma unroll
  for (int dt = 0; dt < 4; ++dt) {
    int d = dt * 16 + c;
    bir[dt] = b_ih[d]; biz[dt] = b_ih[64 + d]; bin[dt] = b_ih[128 + d];
    bhr[dt] = b_hh[d]; bhz[dt] = b_hh[64 + d]; bhn[dt] = b_hh[128 + d];
  }
  for (int tile = blockIdx.x; tile < numTiles; tile += gridDim.x) {
    const int nb0 = tile * 64 + wave * 16;
    const size_t rowbase = (size_t)(nb0 + c) * 64;
    f16x8 aA[2], aH[2];
#pragma unroll
    for (int ks = 0; ks < 2; ++ks) {
      aA[ks] = *(const f16x8*)(aggh + rowbase + ks * 32 + q * 8);
      aH[ks] = *(const f16x8*)(xh + rowbase + ks * 32 + q * 8);
    }
    f32x4 acc[6][4];
#pragma unroll
    for (int g = 0; g < 6; ++g)
#pragma unroll
      for (int dt = 0; dt < 4; ++dt) acc[g][dt] = (f32x4){0.f, 0.f, 0.f, 0.f};
#pragma unroll
    for (int ks = 0; ks < 2; ++ks) {
#pragma unroll
      for (int g = 0; g < 6; ++g) {
        const _Float16* wbase = sW + (g >= 3 ? 192 * WROW : 0) + ((g % 3) * 64) * WROW;
        f16x8 afr = (g < 3) ? aA[ks] : aH[ks];
#pragma unroll
        for (int dt = 0; dt < 4; ++dt) {
          f16x8 bfr = *(const f16x8*)(wbase + (dt * 16 + c) * WROW + ks * 32 + q * 8);
          acc[g][dt] = __builtin_amdgcn_mfma_f32_16x16x32_f16(afr, bfr, acc[g][dt], 0, 0, 0);
        }
      }
    }
    // epilogue: lane (q,c) holds D[node = nb0 + q*4+reg][dim = dt*16+c]
#pragma unroll
    for (int dt = 0; dt < 4; ++dt) {
      int d = dt * 16 + c;
#pragma unroll
      for (int r = 0; r < 4; ++r) {
        int node = nb0 + q * 4 + r;
        if (node < N) {
          float hold = x[(size_t)node * 64 + d];
          float rr = sigmoidf_(acc[0][dt][r] + bir[dt] + acc[3][dt][r] + bhr[dt]);
          float zz = sigmoidf_(acc[1][dt][r] + biz[dt] + acc[4][dt][r] + bhz[dt]);
          float nn = tanhf_(acc[2][dt][r] + bin[dt] + rr * (acc[5][dt][r] + bhn[dt]));
          float out = (1.f - zz) * nn + zz * hold;
          x[(size_t)node * 64 + d] = out;
          xh[(size_t)node * 64 + d] = (_Float16)out;
        }
      }
    }
  }
}

// ---------------- pooling ----------------
__global__ __launch_bounds__(256) void pool_kernel(const float* __restrict__ x,
                                                   const int* __restrict__ batch,
                                                   float* __restrict__ g, int N) {
  int wave = threadIdx.x >> 6, lane = threadIdx.x & 63;
  int n0 = blockIdx.x * 64 + wave * 16;
  if (n0 >= N) return;
  int end = n0 + 16;
  if (end > N) end = N;
  int cur = batch[n0];
  float acc = 0.f;
  for (int n = n0; n < end; ++n) {
    int b = batch[n];
    if (b != cur) {
      atomicAdd(&g[(size_t)cur * 64 + lane], acc);
      acc = 0.f;
      cur = b;
    }
    acc += x[(size_t)n * 64 + lane];
  }
  atomicAdd(&g[(size_t)cur * 64 + lane], acc);
}

// ---------------- final MLP ----------------
__global__ __launch_bounds__(256) void mlp_kernel(const float* __restrict__ g,
                                                  const float* __restrict__ w1,
                                                  const float* __restrict__ b1,
                                                  const float* __restrict__ w2,
                                                  const float* __restrict__ b2,
                                                  const float* __restrict__ w3,
                                                  const float* __restrict__ b3,
                                                  float* __restrict__ out, int G) {
  __shared__ float sG[64 * 64];
  __shared__ float sH1[64 * 32];
  __shared__ float sH2[64 * 16];
  int t = threadIdx.x;
  for (int i = t; i < G * 64; i += 256) sG[i] = g[i];
  __syncthreads();
  for (int o = t; o < G * 32; o += 256) {
    int gi = o >> 5, i = o & 31;
    float a = b1[i];
    for (int k = 0; k < 64; ++k) a += sG[gi * 64 + k] * w1[i * 64 + k];
    sH1[gi * 32 + i] = eluf_(a);
  }
  __syncthreads();
  for (int o = t; o < G * 16; o += 256) {
    int gi = o >> 4, i = o & 15;
    float a = b2[i];
    for (int k = 0; k < 32; ++k) a += sH1[gi * 32 + k] * w2[i * 32 + k];
    sH2[gi * 16 + i] = eluf_(a);
  }
  __syncthreads();
  for (int o = t; o < G; o += 256) {
    float a = b3[0];
    for (int k = 0; k < 16; ++k) a += sH2[o * 16 + k] * w3[k];
    out[o] = a;
  }
}

extern "C" void kernel_launch(void* const* d_in, const int* in_sizes, int n_in,
                              void* d_out, int out_size, void* d_ws, size_t ws_size,
                              hipStream_t stream) {
  const float* conv_w = (const float*)d_in[0];
  const float* w_ih = (const float*)d_in[1];
  const float* w_hh = (const float*)d_in[2];
  const float* b_ih = (const float*)d_in[3];
  const float* b_hh = (const float*)d_in[4];
  const float* fc1_w = (const float*)d_in[5];
  const float* fc1_b = (const float*)d_in[6];
  const float* fc2_w = (const float*)d_in[7];
  const float* fc2_b = (const float*)d_in[8];
  const float* fc3_w = (const float*)d_in[9];
  const float* fc3_b = (const float*)d_in[10];
  const int* ei = (const int*)d_in[11];
  const int* batch = (const int*)d_in[12];
  const int N = in_sizes[12];
  const int E = in_sizes[11] / 2;
  const int G = out_size;
  const int* src = ei;
  const int* dst = ei + E;
  const int nbk = (N + 1023) >> CBITS;      // coarse buckets (<=128)
  const int tiles = (N + 63) / 64;
  const int Npad = tiles * 64;

  char* ws = (char*)d_ws;
  size_t off = 0;
  auto alloc = [&](size_t bytes) -> void* {
    void* p = ws + off;
    off += (bytes + 255) & ~(size_t)255;
    return p;
  };
  float* x = (float*)alloc((size_t)Npad * 64 * 4);
  _Float16* xh = (_Float16*)alloc((size_t)Npad * 64 * 2);
  _Float16* aggh = (_Float16*)alloc((size_t)Npad * 64 * 2);
  float* wc = (float*)alloc((size_t)5 * 192 * 64 * 4);
  float* h1 = (float*)alloc(64 * 4);
  float* gbuf = (float*)alloc((size_t)G * 64 * 4);
  int* offs = (int*)alloc((size_t)(N + 1) * 4);
  int* srcs = (int*)alloc((size_t)E * 4);
  uint2* pairs = (uint2*)alloc((size_t)E * 8);
  int* bh = (int*)alloc(128 * 16 * 4);   // padded bucket counters/cursors
  int* boffs = (int*)alloc(129 * 4);

  // --- CSR build ---
  hipMemsetAsync(bh, 0, 128 * 16 * 4, stream);
  bucket_hist_kernel<<<256, 256, 0, stream>>>(dst, bh, E);
  bucket_scan_kernel<<<1, 128, 0, stream>>>(bh, nbk, boffs, E);
  bucket_fill_kernel<<<(E + FCHUNK - 1) / FCHUNK, 256, 0, stream>>>(src, dst, bh, pairs, E);
  csr_build_kernel<<<nbk, 256, 0, stream>>>(pairs, boffs, offs, srcs, N, E);

  // --- weight fold: wc[l] = conv_w[l] @ w_ih[l]^T ---
  fuse_w_kernel<<<20, 256, 0, stream>>>(conv_w, w_ih, wc);

  // --- layer 0 (closed form) + layer-1 aggregate (deg * h1) ---
  h1_kernel<<<1, 64, 0, stream>>>(b_ih, b_hh, h1);
  bcast_kernel<<<(Npad * 16 + 255) / 256, 256, 0, stream>>>(h1, x, xh, Npad * 16);
  aggdeg_kernel<<<(Npad + 3) / 4, 256, 0, stream>>>(offs, h1, aggh, N, Npad);

  gru_kernel<<<512, 256, 0, stream>>>(aggh, x, xh, wc + 12288, w_hh + 12288,
                                      b_ih + 192, b_hh + 192, N, tiles);
  for (int l = 2; l < 5; ++l) {
    agg_kernel<<<(N + 3) / 4, 256, 0, stream>>>(xh, offs, srcs, aggh, N);
    gru_kernel<<<512, 256, 0, stream>>>(aggh, x, xh, wc + (size_t)l * 12288,
                                        w_hh + (size_t)l * 12288, b_ih + (size_t)l * 192,
                                        b_hh + (size_t)l * 192, N, tiles);
  }

  hipMemsetAsync(gbuf, 0, (size_t)G * 64 * 4, stream);
  pool_kernel<<<(N + 63) / 64, 256, 0, stream>>>(x, batch, gbuf, N);
  mlp_kernel<<<1, 256, 0, stream>>>(gbuf, fc1_w, fc1_b, fc2_w, fc2_b, fc3_w, fc3_b,
                                    (float*)d_out, G);
}

// Round 5
// 538.349 us; speedup vs baseline: 2.2125x; 1.1285x over previous
//
#include <hip/hip_runtime.h>
#include <math.h>

typedef _Float16 f16x2 __attribute__((ext_vector_type(2)));
typedef _Float16 f16x4 __attribute__((ext_vector_type(4)));
typedef _Float16 f16x8 __attribute__((ext_vector_type(8)));
typedef float f32x4 __attribute__((ext_vector_type(4)));

#define CBITS 10      // 1024 nodes per coarse bucket
#define FCHUNK 4096   // edges per fill block (16KB LDS staging)
#define WROW 72       // LDS weight row stride in f16 (64 + 8 pad; 16B aligned, 2-way banks = free)

__device__ __forceinline__ float sigmoidf_(float v) {
  return 1.0f / (1.0f + __expf(-v));
}
__device__ __forceinline__ float tanhf_(float v) {
  v = fminf(fmaxf(v, -15.f), 15.f);
  float e = __expf(2.f * v);
  return (e - 1.f) / (e + 1.f);
}
__device__ __forceinline__ float eluf_(float v) { return v > 0.f ? v : (__expf(v) - 1.f); }

// ---------------- fuse conv into GRU input weights: Wc[j][c] = sum_k W[c][k] * w_ih[j][k] ----------------
__global__ __launch_bounds__(256) void fuse_w_kernel(const float* __restrict__ conv_w,
                                                     const float* __restrict__ w_ih,
                                                     float* __restrict__ wc) {
  const int l = blockIdx.x >> 2;
  const int j0 = (blockIdx.x & 3) * 48;
  const float* W = conv_w + (size_t)l * 4096;   // [c][k]
  const float* wi = w_ih + (size_t)l * 12288;   // [j][k]
  float* out = wc + (size_t)l * 12288;          // [j][c]
  __shared__ float sWt[64 * 68];
  __shared__ float sI[48 * 64];
  const int t = threadIdx.x;
  for (int i = t; i < 4096; i += 256) sWt[(i & 63) * 68 + (i >> 6)] = W[i];
  for (int i = t; i < 3072; i += 256) sI[i] = wi[j0 * 64 + i];
  __syncthreads();
#pragma unroll
  for (int r = 0; r < 3; ++r) {
    int u = t + 256 * r;
    int j = u >> 4, cg = (u & 15) * 4;
    float4 a = {0.f, 0.f, 0.f, 0.f};
    for (int k = 0; k < 64; ++k) {
      float4 w = *(const float4*)(sWt + k * 68 + cg);
      float s = sI[j * 64 + k];
      a.x += w.x * s; a.y += w.y * s; a.z += w.z * s; a.w += w.w * s;
    }
    *(float4*)(out + (size_t)(j0 + j) * 64 + cg) = a;
  }
}

// ---------------- CSR build: coarse-bucket counting sort (pairs packed: src<<10 | local_dst) ----------------
__global__ __launch_bounds__(256) void bucket_hist_kernel(const int* __restrict__ dst,
                                                          int* __restrict__ bh, int E) {
  __shared__ int h[128];
  const int t = threadIdx.x;
  if (t < 128) h[t] = 0;
  __syncthreads();
  for (int e = blockIdx.x * 256 + t; e < E; e += gridDim.x * 256)
    atomicAdd(&h[dst[e] >> CBITS], 1);
  __syncthreads();
  if (t < 128 && h[t]) atomicAdd(&bh[t * 16], h[t]);  // padded counters: 1 line each
}

__global__ __launch_bounds__(128) void bucket_scan_kernel(int* __restrict__ bh, int nbk,
                                                          int* __restrict__ boffs, int E) {
  __shared__ int s[128];
  const int t = threadIdx.x;
  int v = (t < nbk) ? bh[t * 16] : 0;
  s[t] = v;
  __syncthreads();
  for (int o = 1; o < 128; o <<= 1) {
    int a = (t >= o) ? s[t - o] : 0;
    __syncthreads();
    s[t] += a;
    __syncthreads();
  }
  if (t < nbk) {
    int ex = s[t] - v;
    boffs[t] = ex;
    bh[t * 16] = ex;  // becomes the reservation cursor
  }
  if (t == 0) boffs[nbk] = E;
}

__global__ __launch_bounds__(256) void bucket_fill_kernel(const int* __restrict__ src,
                                                          const int* __restrict__ dst,
                                                          int* __restrict__ bcur,
                                                          unsigned* __restrict__ pairs, int E) {
  __shared__ unsigned staged[FCHUNK];
  __shared__ int h[128], lbase[128], gbase[128], lcur[128];
  const int t = threadIdx.x;
  const int e0 = blockIdx.x * FCHUNK;
  int cnt = E - e0;
  if (cnt > FCHUNK) cnt = FCHUNK;
  if (t < 128) h[t] = 0;
  __syncthreads();
  for (int i = t; i < cnt; i += 256) atomicAdd(&h[dst[e0 + i] >> CBITS], 1);
  __syncthreads();
  if (t < 128) lcur[t] = h[t];
  __syncthreads();
  for (int o = 1; o < 128; o <<= 1) {
    int a = 0;
    if (t < 128 && t >= o) a = lcur[t - o];
    __syncthreads();
    if (t < 128) lcur[t] += a;
    __syncthreads();
  }
  if (t < 128) {
    int ex = lcur[t] - h[t];
    lbase[t] = ex;
    if (h[t]) gbase[t] = atomicAdd(&bcur[t * 16], h[t]);
    lcur[t] = ex;
  }
  __syncthreads();
  for (int i = t; i < cnt; i += 256) {
    int d = dst[e0 + i];
    int b = d >> CBITS;
    int p = atomicAdd(&lcur[b], 1);
    staged[p] = ((unsigned)src[e0 + i] << CBITS) | (unsigned)(d & ((1 << CBITS) - 1));
  }
  __syncthreads();
  // flush: consecutive staged positions within a bucket -> consecutive global positions
  for (int i = t; i < cnt; i += 256) {
    unsigned pr = staged[i];
    // recover bucket: staged order groups by bucket; find bucket via local dst? We need bucket id.
    // local_dst alone doesn't give bucket; recompute via position: i falls in [lbase[b], lbase[b]+h[b]).
    // Instead store bucket implicitly: binary search over lbase is overkill -> carry bucket in upper bits?
    // src<<10 uses bits [10,27); bucket fits in bits [27,32) only if nbk<=31. nbk=98 -> no.
    // Use a second pass over buckets: each thread walks its strided positions once per bucket range.
    pairs[0] = pr;  // placeholder (overwritten below) -- never executed; see flush loop after
    break;
  }
  // proper flush: iterate buckets owned by groups of threads using lbase/h tables
  __syncthreads();
  for (int i = t; i < cnt; i += 256) {
    unsigned pr = staged[i];
    (void)pr;
  }
  // NOTE: flush handled in flush_kernel-free way below using per-thread scan of bucket table
  __syncthreads();
  // Final (correct) flush: for each staged index i, find its bucket by scanning the 128-entry
  // lbase table held in LDS (binary search, table is sorted).
  for (int i = t; i < cnt; i += 256) {
    unsigned pr = staged[i];
    int lo = 0, hi = 127;
    // largest b with lbase[b] <= i  (lbase is non-decreasing; empty buckets share values)
    while (lo < hi) {
      int mid = (lo + hi + 1) >> 1;
      if (lbase[mid] <= i) lo = mid; else hi = mid - 1;
    }
    // skip empty buckets that share lbase: ensure i < lbase[lo]+h[lo] by walking back
    while (h[lo] == 0 || i >= lbase[lo] + h[lo]) --lo;  // safety net (at most a few steps)
    pairs[gbase[lo] + (i - lbase[lo])] = pr;
  }
}

__global__ __launch_bounds__(256) void csr_build_kernel(const unsigned* __restrict__ pairs,
                                                        const int* __restrict__ boffs,
                                                        int* __restrict__ offs,
                                                        int* __restrict__ srcs, int N, int E) {
  const int b = blockIdx.x, t = threadIdx.x;
  const int nbase = b << CBITS;
  __shared__ int deg[1024];
  __shared__ int ssc[256];
  for (int i = t; i < 1024; i += 256) deg[i] = 0;
  __syncthreads();
  const int beg = boffs[b], end = boffs[b + 1];
  for (int e = beg + t; e < end; e += 256) atomicAdd(&deg[pairs[e] & 1023], 1);
  __syncthreads();
  int d0 = deg[4 * t], d1 = deg[4 * t + 1], d2 = deg[4 * t + 2], d3 = deg[4 * t + 3];
  int s = d0 + d1 + d2 + d3;
  ssc[t] = s;
  __syncthreads();
  for (int o = 1; o < 256; o <<= 1) {
    int a = (t >= o) ? ssc[t - o] : 0;
    __syncthreads();
    ssc[t] += a;
    __syncthreads();
  }
  int base = beg + ssc[t] - s;
  int c0 = base, c1 = c0 + d0, c2 = c1 + d1, c3 = c2 + d2;
  if (nbase + 4 * t + 0 < N) offs[nbase + 4 * t + 0] = c0;
  if (nbase + 4 * t + 1 < N) offs[nbase + 4 * t + 1] = c1;
  if (nbase + 4 * t + 2 < N) offs[nbase + 4 * t + 2] = c2;
  if (nbase + 4 * t + 3 < N) offs[nbase + 4 * t + 3] = c3;
  deg[4 * t] = c0; deg[4 * t + 1] = c1; deg[4 * t + 2] = c2; deg[4 * t + 3] = c3;
  if (b == 0 && t == 0) offs[N] = E;
  __syncthreads();
  for (int e = beg + t; e < end; e += 256) {
    unsigned p = pairs[e];
    int pos = atomicAdd(&deg[p & 1023], 1);
    srcs[pos] = (int)(p >> CBITS);
  }
}

// ---------------- layer-0 algebra: h1 = GRU(0, 0) is one 64-vector ----------------
__global__ __launch_bounds__(64) void h1_kernel(const float* __restrict__ b_ih,
                                                const float* __restrict__ b_hh,
                                                float* __restrict__ h1) {
  int d = threadIdx.x;
  float r = sigmoidf_(b_ih[d] + b_hh[d]);
  float z = sigmoidf_(b_ih[64 + d] + b_hh[64 + d]);
  float n = tanhf_(b_ih[128 + d] + r * b_hh[128 + d]);
  h1[d] = (1.f - z) * n;
}

// broadcast h1 into xh AND write layer-1 aggregate aggh = deg * h1 (merged kernel)
__global__ __launch_bounds__(256) void bcast_kernel(const int* __restrict__ offs,
                                                    const float* __restrict__ h1,
                                                    _Float16* __restrict__ xh,
                                                    _Float16* __restrict__ aggh,
                                                    int N, int units) {
  int idx = blockIdx.x * 256 + threadIdx.x;  // one f16x2 (2 dims) per thread
  if (idx >= units) return;
  int v = idx >> 5, lp = idx & 31;
  float2 hh = *(const float2*)(h1 + lp * 2);
  f16x2 hv;
  hv[0] = (_Float16)hh.x; hv[1] = (_Float16)hh.y;
  *(f16x2*)(xh + (size_t)idx * 2) = hv;
  float dg = (v < N) ? (float)(offs[v + 1] - offs[v]) : 0.f;
  f16x2 av;
  av[0] = (_Float16)(dg * hh.x); av[1] = (_Float16)(dg * hh.y);
  *(f16x2*)(aggh + (size_t)idx * 2) = av;
}

// ---------------- aggregate (f16 gather, 4 edges per load instruction) ----------------
__global__ __launch_bounds__(256) void agg_kernel(const _Float16* __restrict__ xh,
                                                  const int* __restrict__ offs,
                                                  const int* __restrict__ srcs,
                                                  _Float16* __restrict__ aggh, int N) {
  int wave = threadIdx.x >> 6, lane = threadIdx.x & 63;
  int v = blockIdx.x * 4 + wave;
  if (v >= N) return;
  const int beg = offs[v], end = offs[v + 1];
  const int deg = end - beg;
  const int q = lane >> 4;    // which edge of the 4-group this lane serves
  const int lp = lane & 15;   // f16x4 position within the row
  float4 acc = {0.f, 0.f, 0.f, 0.f};
  for (int base = 0; base < deg; base += 64) {
    const int cnt = min(64, deg - base);
    int sidx = srcs[beg + base + lane];  // one vector load: 64 indices (srcs padded +64)
#pragma unroll 2
    for (int e = 0; e < cnt; e += 4) {
      int myedge = e + q;
      int s = __shfl(sidx, myedge);
      f16x4 vv = *(const f16x4*)(xh + (size_t)s * 64 + lp * 4);
      if (myedge < cnt) {
        acc.x += (float)vv[0]; acc.y += (float)vv[1];
        acc.z += (float)vv[2]; acc.w += (float)vv[3];
      }
    }
  }
  // combine quarters: total = sum over lanes lp, lp+16, lp+32, lp+48
  acc.x += __shfl_xor(acc.x, 16); acc.y += __shfl_xor(acc.y, 16);
  acc.z += __shfl_xor(acc.z, 16); acc.w += __shfl_xor(acc.w, 16);
  acc.x += __shfl_xor(acc.x, 32); acc.y += __shfl_xor(acc.y, 32);
  acc.z += __shfl_xor(acc.z, 32); acc.w += __shfl_xor(acc.w, 32);
  if (q == 0) {
    f16x4 o;
    o[0] = (_Float16)acc.x; o[1] = (_Float16)acc.y;
    o[2] = (_Float16)acc.z; o[3] = (_Float16)acc.w;
    *(f16x4*)(aggh + (size_t)v * 64 + lp * 4) = o;
  }
}

// ---------------- MFMA GRU: xh = GRUCell(aggh @ Wc^T, xh)  (f16 state only) ----------------
__global__ __launch_bounds__(256) void gru_kernel(const _Float16* __restrict__ aggh,
                                                  _Float16* __restrict__ xh,
                                                  const float* __restrict__ wih,
                                                  const float* __restrict__ whh,
                                                  const float* __restrict__ b_ih,
                                                  const float* __restrict__ b_hh,
                                                  int N, int numTiles) {
  __shared__ _Float16 sW[2 * 192 * WROW];  // 54 KB
  const int t = threadIdx.x;
  for (int i = t; i < 6144; i += 256) {  // 2 mats * 192 rows * 16 float4-units (3072/mat)
    int mat = (i >= 3072) ? 1 : 0;
    int r = (i - mat * 3072) >> 4;
    int c4 = i & 15;
    const float* srcp = (mat ? whh : wih) + r * 64 + c4 * 4;
    float4 v = *(const float4*)srcp;
    f16x4 hv;
    hv[0] = (_Float16)v.x; hv[1] = (_Float16)v.y;
    hv[2] = (_Float16)v.z; hv[3] = (_Float16)v.w;
    *(f16x4*)(sW + mat * 192 * WROW + r * WROW + c4 * 4) = hv;
  }
  __syncthreads();
  const int wave = t >> 6, lane = t & 63;
  const int q = lane >> 4, c = lane & 15;
  float bir[4], biz[4], bin[4], bhr[4], bhz[4], bhn[4];
#pragma unroll
  for (int dt = 0; dt < 4; ++dt) {
    int d = dt * 16 + c;
    bir[dt] = b_ih[d]; biz[dt] = b_ih[64 + d]; bin[dt] = b_ih[128 + d];
    bhr[dt] = b_hh[d]; bhz[dt] = b_hh[64 + d]; bhn[dt] = b_hh[128 + d];
  }
  for (int tile = blockIdx.x; tile < numTiles; tile += gridDim.x) {
    const int nb0 = tile * 64 + wave * 16;
    const size_t rowbase = (size_t)(nb0 + c) * 64;
    f16x8 aA[2], aH[2];
#pragma unroll
    for (int ks = 0; ks < 2; ++ks) {
      aA[ks] = *(const f16x8*)(aggh + rowbase + ks * 32 + q * 8);
      aH[ks] = *(const f16x8*)(xh + rowbase + ks * 32 + q * 8);
    }
    f32x4 acc[6][4];
#pragma unroll
    for (int g = 0; g < 6; ++g)
#pragma unroll
      for (int dt = 0; dt < 4; ++dt) acc[g][dt] = (f32x4){0.f, 0.f, 0.f, 0.f};
#pragma unroll
    for (int ks = 0; ks < 2; ++ks) {
#pragma unroll
      for (int g = 0; g < 6; ++g) {
        const _Float16* wbase = sW + (g >= 3 ? 192 * WROW : 0) + ((g % 3) * 64) * WROW;
        f16x8 afr = (g < 3) ? aA[ks] : aH[ks];
#pragma unroll
        for (int dt = 0; dt < 4; ++dt) {
          f16x8 bfr = *(const f16x8*)(wbase + (dt * 16 + c) * WROW + ks * 32 + q * 8);
          acc[g][dt] = __builtin_amdgcn_mfma_f32_16x16x32_f16(afr, bfr, acc[g][dt], 0, 0, 0);
        }
      }
    }
    // epilogue: lane (q,c) holds D[node = nb0 + q*4+r][dim = dt*16+c]
#pragma unroll
    for (int dt = 0; dt < 4; ++dt) {
      int d = dt * 16 + c;
#pragma unroll
      for (int r = 0; r < 4; ++r) {
        int node = nb0 + q * 4 + r;
        if (node < N) {
          float hold = (float)xh[(size_t)node * 64 + d];
          float rr = sigmoidf_(acc[0][dt][r] + bir[dt] + acc[3][dt][r] + bhr[dt]);
          float zz = sigmoidf_(acc[1][dt][r] + biz[dt] + acc[4][dt][r] + bhz[dt]);
          float nn = tanhf_(acc[2][dt][r] + bin[dt] + rr * (acc[5][dt][r] + bhn[dt]));
          float out = (1.f - zz) * nn + zz * hold;
          xh[(size_t)node * 64 + d] = (_Float16)out;
        }
      }
    }
  }
}

// ---------------- pooling (f16 input) ----------------
__global__ __launch_bounds__(256) void pool_kernel(const _Float16* __restrict__ xh,
                                                   const int* __restrict__ batch,
                                                   float* __restrict__ g, int N) {
  int wave = threadIdx.x >> 6, lane = threadIdx.x & 63;
  int n0 = blockIdx.x * 64 + wave * 16;
  if (n0 >= N) return;
  int end = n0 + 16;
  if (end > N) end = N;
  int cur = batch[n0];
  float acc = 0.f;
  for (int n = n0; n < end; ++n) {
    int b = batch[n];
    if (b != cur) {
      atomicAdd(&g[(size_t)cur * 64 + lane], acc);
      acc = 0.f;
      cur = b;
    }
    acc += (float)xh[(size_t)n * 64 + lane];
  }
  atomicAdd(&g[(size_t)cur * 64 + lane], acc);
}

// ---------------- final MLP ----------------
__global__ __launch_bounds__(256) void mlp_kernel(const float* __restrict__ g,
                                                  const float* __restrict__ w1,
                                                  const float* __restrict__ b1,
                                                  const float* __restrict__ w2,
                                                  const float* __restrict__ b2,
                                                  const float* __restrict__ w3,
                                                  const float* __restrict__ b3,
                                                  float* __restrict__ out, int G) {
  __shared__ float sG[64 * 64];
  __shared__ float sH1[64 * 32];
  __shared__ float sH2[64 * 16];
  int t = threadIdx.x;
  for (int i = t; i < G * 64; i += 256) sG[i] = g[i];
  __syncthreads();
  for (int o = t; o < G * 32; o += 256) {
    int gi = o >> 5, i = o & 31;
    float a = b1[i];
    for (int k = 0; k < 64; ++k) a += sG[gi * 64 + k] * w1[i * 64 + k];
    sH1[gi * 32 + i] = eluf_(a);
  }
  __syncthreads();
  for (int o = t; o < G * 16; o += 256) {
    int gi = o >> 4, i = o & 15;
    float a = b2[i];
    for (int k = 0; k < 32; ++k) a += sH1[gi * 32 + k] * w2[i * 32 + k];
    sH2[gi * 16 + i] = eluf_(a);
  }
  __syncthreads();
  for (int o = t; o < G; o += 256) {
    float a = b3[0];
    for (int k = 0; k < 16; ++k) a += sH2[o * 16 + k] * w3[k];
    out[o] = a;
  }
}

extern "C" void kernel_launch(void* const* d_in, const int* in_sizes, int n_in,
                              void* d_out, int out_size, void* d_ws, size_t ws_size,
                              hipStream_t stream) {
  const float* conv_w = (const float*)d_in[0];
  const float* w_ih = (const float*)d_in[1];
  const float* w_hh = (const float*)d_in[2];
  const float* b_ih = (const float*)d_in[3];
  const float* b_hh = (const float*)d_in[4];
  const float* fc1_w = (const float*)d_in[5];
  const float* fc1_b = (const float*)d_in[6];
  const float* fc2_w = (const float*)d_in[7];
  const float* fc2_b = (const float*)d_in[8];
  const float* fc3_w = (const float*)d_in[9];
  const float* fc3_b = (const float*)d_in[10];
  const int* ei = (const int*)d_in[11];
  const int* batch = (const int*)d_in[12];
  const int N = in_sizes[12];
  const int E = in_sizes[11] / 2;
  const int G = out_size;
  const int* src = ei;
  const int* dst = ei + E;
  const int nbk = (N + 1023) >> CBITS;      // coarse buckets (<=128)
  const int tiles = (N + 63) / 64;
  const int Npad = tiles * 64;

  char* ws = (char*)d_ws;
  size_t off = 0;
  auto alloc = [&](size_t bytes) -> void* {
    void* p = ws + off;
    off += (bytes + 255) & ~(size_t)255;
    return p;
  };
  _Float16* xh = (_Float16*)alloc((size_t)Npad * 64 * 2);
  _Float16* aggh = (_Float16*)alloc((size_t)Npad * 64 * 2);
  float* wc = (float*)alloc((size_t)5 * 192 * 64 * 4);
  float* h1 = (float*)alloc(64 * 4);
  float* gbuf = (float*)alloc((size_t)G * 64 * 4);
  int* offs = (int*)alloc((size_t)(N + 1) * 4);
  int* srcs = (int*)alloc((size_t)(E + 64) * 4);   // +64 pad: agg loads chunk of 64 indices
  unsigned* pairs = (unsigned*)alloc((size_t)E * 4);
  int* bh = (int*)alloc(128 * 16 * 4);
  int* boffs = (int*)alloc(129 * 4);

  // --- CSR build ---
  hipMemsetAsync(bh, 0, 128 * 16 * 4, stream);
  bucket_hist_kernel<<<256, 256, 0, stream>>>(dst, bh, E);
  bucket_scan_kernel<<<1, 128, 0, stream>>>(bh, nbk, boffs, E);
  bucket_fill_kernel<<<(E + FCHUNK - 1) / FCHUNK, 256, 0, stream>>>(src, dst, bh, pairs, E);
  csr_build_kernel<<<nbk, 256, 0, stream>>>(pairs, boffs, offs, srcs, N, E);

  // --- weight fold: wc[l] = conv_w[l] @ w_ih[l]^T ---
  fuse_w_kernel<<<20, 256, 0, stream>>>(conv_w, w_ih, wc);

  // --- layer 0 (closed form) + layer-1 aggregate (deg * h1), merged ---
  h1_kernel<<<1, 64, 0, stream>>>(b_ih, b_hh, h1);
  bcast_kernel<<<(Npad * 32 + 255) / 256, 256, 0, stream>>>(offs, h1, xh, aggh, N, Npad * 32);

  gru_kernel<<<512, 256, 0, stream>>>(aggh, xh, wc + 12288, w_hh + 12288,
                                      b_ih + 192, b_hh + 192, N, tiles);
  for (int l = 2; l < 5; ++l) {
    agg_kernel<<<(N + 3) / 4, 256, 0, stream>>>(xh, offs, srcs, aggh, N);
    gru_kernel<<<512, 256, 0, stream>>>(aggh, xh, wc + (size_t)l * 12288,
                                        w_hh + (size_t)l * 12288, b_ih + (size_t)l * 192,
                                        b_hh + (size_t)l * 192, N, tiles);
  }

  hipMemsetAsync(gbuf, 0, (size_t)G * 64 * 4, stream);
  pool_kernel<<<(N + 63) / 64, 256, 0, stream>>>(xh, batch, gbuf, N);
  mlp_kernel<<<1, 256, 0, stream>>>(gbuf, fc1_w, fc1_b, fc2_w, fc2_b, fc3_w, fc3_b,
                                    (float*)d_out, G);
}